// Round 3
// baseline (223.295 us; speedup 1.0000x reference)
//
#include <hip/hip_runtime.h>

#define BB 2
#define CC 64
#define HH 128
#define WW 128
#define NN (HH*WW)          // 16384 queries per batch
#define MM ((HH/2)*(WW/2))  // 4096 keys per batch
#define CV 32

typedef __attribute__((ext_vector_type(8))) short bf16x8;
typedef __attribute__((ext_vector_type(4))) float f32x4;
typedef unsigned int uint32;

union U8 { bf16x8 v; uint32 u[4]; };

__device__ __forceinline__ short f2bf(float f) {
    union { float f; unsigned u; } v; v.f = f;
    unsigned u = v.u + 0x7fffu + ((v.u >> 16) & 1u);   // RNE
    return (short)(u >> 16);
}
__device__ __forceinline__ uint32 pack2bf(float lo, float hi) {
    return (uint32)(unsigned short)f2bf(lo) | ((uint32)(unsigned short)f2bf(hi) << 16);
}
// truncation pack: 3 ops; downward bias cancels in softmax ratio P/l
__device__ __forceinline__ uint32 pack2bf_trunc(float lo, float hi) {
    union { float f; uint32 u; } a, b; a.f = lo; b.f = hi;
    return (a.u >> 16) | (b.u & 0xffff0000u);
}

// ---------------------------------------------------------------------------
// Kernel 1: conv1x1 projections + 2x2 maxpool. z=0: theta+phi, z=1: g.
// Weights read via wave-uniform global indices -> s_load + SGPR-operand
// v_fmac (NO LDS for weights — that was the R1/R2 75us mistake).
// Grid (64, B, 2) x 256 threads; block = 2 image rows.
// ---------------------------------------------------------------------------
__global__ __launch_bounds__(256) void proj_kernel(
    const float* __restrict__ x, const float* __restrict__ wt,
    const float* __restrict__ wp, const float* __restrict__ wg,
    short* __restrict__ Qb, short* __restrict__ Kb, short* __restrict__ Vt)
{
    __shared__ float pg_lds[256][33];   // +1 pad
    int tid = threadIdx.x, z = blockIdx.z;
    int s = blockIdx.x, b = blockIdx.y;
    int r = tid >> 7, wc = tid & 127;
    int n = (2*s + r)*WW + wc;

    float xv[64];
    #pragma unroll
    for (int c = 0; c < 64; ++c) xv[c] = x[((b*CC + c) << 14) + n];

    if (z == 0) {
        float o8[8];
        #pragma unroll
        for (int o = 0; o < 8; ++o) {
            float a = 0.f;
            #pragma unroll
            for (int c = 0; c < 64; ++c) a += wt[o*64 + c]*xv[c];
            o8[o] = a;
        }
        uint4 val;
        val.x = pack2bf(o8[0], o8[1]); val.y = pack2bf(o8[2], o8[3]);
        val.z = pack2bf(o8[4], o8[5]); val.w = pack2bf(o8[6], o8[7]);
        ((uint4*)Qb)[b*NN + n] = val;
        #pragma unroll
        for (int o = 0; o < 8; ++o) {
            float a = 0.f;
            #pragma unroll
            for (int c = 0; c < 64; ++c) a += wp[o*64 + c]*xv[c];
            pg_lds[tid][o] = a;
        }
        __syncthreads();
        if (tid < 64) {
            int w2 = tid, t00 = 2*w2, t01 = t00+1, t10 = 128+2*w2, t11 = t10+1;
            int m = s*64 + w2;
            float kf[8];
            #pragma unroll
            for (int o = 0; o < 8; ++o)
                kf[o] = fmaxf(fmaxf(pg_lds[t00][o], pg_lds[t01][o]),
                              fmaxf(pg_lds[t10][o], pg_lds[t11][o]));
            uint4 val2;
            val2.x = pack2bf(kf[0], kf[1]); val2.y = pack2bf(kf[2], kf[3]);
            val2.z = pack2bf(kf[4], kf[5]); val2.w = pack2bf(kf[6], kf[7]);
            ((uint4*)Kb)[b*MM + m] = val2;
        }
    } else {
        #pragma unroll
        for (int o = 0; o < 32; ++o) {
            float a = 0.f;
            #pragma unroll
            for (int c = 0; c < 64; ++c) a += wg[o*64 + c]*xv[c];
            pg_lds[tid][o] = a;
        }
        __syncthreads();
        int g = tid >> 6, w2 = tid & 63;
        int t00 = 2*w2, t01 = t00+1, t10 = 128+2*w2, t11 = t10+1;
        int m = s*64 + w2;
        #pragma unroll
        for (int j = 0; j < 8; ++j) {
            int o = g*8 + j;
            float a = fmaxf(fmaxf(pg_lds[t00][o], pg_lds[t01][o]),
                            fmaxf(pg_lds[t10][o], pg_lds[t11][o]));
            Vt[(b*CV + o)*MM + m] = f2bf(a);
        }
    }
}

// ---------------------------------------------------------------------------
// Kernel 2: fused attention + normalize + w_o + residual.
// Branch-free 64-key loop body: K loads unconditional in ALL quads (upper
// quads hit bq's zeros — finite values so no NaN*0), prefetch address
// clamped by scalar min instead of a tail branch.
// Grid = B*N/64 = 512 blocks x 256 threads.
// ---------------------------------------------------------------------------
__global__ __launch_bounds__(256) void attn_kernel(
    const short* __restrict__ Qb, const short* __restrict__ Kb,
    const short* __restrict__ Vt, const float* __restrict__ x,
    const float* __restrict__ wo, const float* __restrict__ gamma,
    float* __restrict__ out)
{
    int tid = threadIdx.x, wave = tid >> 6, lane = tid & 63;
    int quad = lane >> 4, c15 = lane & 15;
    int gq = blockIdx.x*4 + wave;
    int b = gq >> 10;
    int qbase = (gq & 1023) << 4;

    const f32x4 zero4 = {0.f, 0.f, 0.f, 0.f};
    bf16x8 zero8 = (bf16x8)0;

    // Q as score-MFMA B-operand: B[k=ch][n=q]; quads 1-3 MUST be zero.
    bf16x8 bq = (quad == 0) ? ((const bf16x8*)Qb)[b*NN + qbase + c15] : zero8;

    const short* Kbb = Kb + b*MM*8;
    const short* V0b = Vt + (b*CV + c15)*MM;
    const short* V1b = Vt + (b*CV + 16 + c15)*MM;

    f32x4 D0 = zero4, D1 = zero4;
    float l_part = 0.f;

    // current-stage regs: 64 keys = 2 half-chunks of 32
    bf16x8 kc[4];
    uint2 vc0[4], vc1[4];
    #pragma unroll
    for (int h = 0; h < 2; ++h) {
        int k = h*32;
        kc[2*h]   = *(const bf16x8*)(Kbb + (k + c15)*8);
        kc[2*h+1] = *(const bf16x8*)(Kbb + (k + 16 + c15)*8);
        vc0[2*h]   = *(const uint2*)(V0b + k + quad*4);
        vc0[2*h+1] = *(const uint2*)(V0b + k + 16 + quad*4);
        vc1[2*h]   = *(const uint2*)(V1b + k + quad*4);
        vc1[2*h+1] = *(const uint2*)(V1b + k + 16 + quad*4);
    }

    #pragma unroll 2
    for (int sc = 0; sc < 64; ++sc) {
        int kn = (sc + 1)*64;
        kn = (kn > MM - 64) ? (MM - 64) : kn;   // scalar clamp, no branch
        bf16x8 nk[4];
        uint2 nv0[4], nv1[4];
        #pragma unroll
        for (int h = 0; h < 2; ++h) {
            int k = kn + h*32;
            nk[2*h]   = *(const bf16x8*)(Kbb + (k + c15)*8);
            nk[2*h+1] = *(const bf16x8*)(Kbb + (k + 16 + c15)*8);
            nv0[2*h]   = *(const uint2*)(V0b + k + quad*4);
            nv0[2*h+1] = *(const uint2*)(V0b + k + 16 + quad*4);
            nv1[2*h]   = *(const uint2*)(V1b + k + quad*4);
            nv1[2*h+1] = *(const uint2*)(V1b + k + 16 + quad*4);
        }
        #pragma unroll
        for (int h = 0; h < 2; ++h) {
            f32x4 s0 = __builtin_amdgcn_mfma_f32_16x16x32_bf16(kc[2*h],   bq, zero4, 0, 0, 0);
            f32x4 s1 = __builtin_amdgcn_mfma_f32_16x16x32_bf16(kc[2*h+1], bq, zero4, 0, 0, 0);
            float p00 = __expf(s0[0]), p01 = __expf(s0[1]), p02 = __expf(s0[2]), p03 = __expf(s0[3]);
            float p10 = __expf(s1[0]), p11 = __expf(s1[1]), p12 = __expf(s1[2]), p13 = __expf(s1[3]);
            l_part += ((p00 + p01) + (p02 + p03)) + ((p10 + p11) + (p12 + p13));
            U8 bp;
            bp.u[0] = pack2bf_trunc(p00, p01); bp.u[1] = pack2bf_trunc(p02, p03);
            bp.u[2] = pack2bf_trunc(p10, p11); bp.u[3] = pack2bf_trunc(p12, p13);
            U8 av0, av1;
            av0.u[0] = vc0[2*h].x; av0.u[1] = vc0[2*h].y;
            av0.u[2] = vc0[2*h+1].x; av0.u[3] = vc0[2*h+1].y;
            av1.u[0] = vc1[2*h].x; av1.u[1] = vc1[2*h].y;
            av1.u[2] = vc1[2*h+1].x; av1.u[3] = vc1[2*h+1].y;
            D0 = __builtin_amdgcn_mfma_f32_16x16x32_bf16(av0.v, bp.v, D0, 0, 0, 0);
            D1 = __builtin_amdgcn_mfma_f32_16x16x32_bf16(av1.v, bp.v, D1, 0, 0, 0);
        }
        #pragma unroll
        for (int i = 0; i < 4; ++i) { kc[i] = nk[i]; vc0[i] = nv0[i]; vc1[i] = nv1[i]; }
    }

    float l = l_part;
    l += __shfl_xor(l, 16);
    l += __shfl_xor(l, 32);
    float rl = 1.0f / l;

    U8 By;
    By.u[0] = pack2bf(D0[0]*rl, D0[1]*rl); By.u[1] = pack2bf(D0[2]*rl, D0[3]*rl);
    By.u[2] = pack2bf(D1[0]*rl, D1[1]*rl); By.u[3] = pack2bf(D1[2]*rl, D1[3]*rl);

    float gam = gamma[0];
    #pragma unroll
    for (int t = 0; t < 4; ++t) {
        int co = t*16 + c15;
        float4 wlo = *(const float4*)(wo + co*32 + quad*4);
        float4 whi = *(const float4*)(wo + co*32 + 16 + quad*4);
        U8 aw;
        aw.u[0] = pack2bf(wlo.x, wlo.y); aw.u[1] = pack2bf(wlo.z, wlo.w);
        aw.u[2] = pack2bf(whi.x, whi.y); aw.u[3] = pack2bf(whi.z, whi.w);
        f32x4 o2 = __builtin_amdgcn_mfma_f32_16x16x32_bf16(aw.v, By.v, zero4, 0, 0, 0);
        #pragma unroll
        for (int r2 = 0; r2 < 4; ++r2) {
            int co_r = t*16 + quad*4 + r2;
            int idx = ((b*CC + co_r) << 14) + qbase + c15;
            out[idx] = x[idx] + gam*o2[r2];
        }
    }
}

// ---------------------------------------------------------------------------
// Workspace: Qb 512K @ 0, Kb 128K @ 524288, Vt 512K @ 655360.
// ---------------------------------------------------------------------------
extern "C" void kernel_launch(void* const* d_in, const int* in_sizes, int n_in,
                              void* d_out, int out_size, void* d_ws, size_t ws_size,
                              hipStream_t stream) {
    const float* x     = (const float*)d_in[0];
    const float* wt    = (const float*)d_in[1];
    const float* wp    = (const float*)d_in[2];
    const float* wg    = (const float*)d_in[3];
    const float* wo    = (const float*)d_in[4];
    const float* gamma = (const float*)d_in[5];
    float* out = (float*)d_out;

    char* ws = (char*)d_ws;
    short* Qb = (short*)(ws);
    short* Kb = (short*)(ws + 524288);
    short* Vt = (short*)(ws + 655360);

    dim3 g1(HH/2, BB, 2);
    proj_kernel<<<g1, 256, 0, stream>>>(x, wt, wp, wg, Qb, Kb, Vt);
    attn_kernel<<<BB*NN/64, 256, 0, stream>>>(Qb, Kb, Vt, x, wo, gamma, out);
}

// Round 4
// 183.339 us; speedup vs baseline: 1.2179x; 1.2179x over previous
//
#include <hip/hip_runtime.h>

#define BB 2
#define CC 64
#define HH 128
#define WW 128
#define NN (HH*WW)          // 16384 queries per batch
#define MM ((HH/2)*(WW/2))  // 4096 keys per batch
#define CV 32
#define LOG2E 1.44269504088896f

typedef __attribute__((ext_vector_type(8))) short bf16x8;
typedef __attribute__((ext_vector_type(4))) float f32x4;
typedef unsigned int uint32;

union U8 { bf16x8 v; uint32 u[4]; };

__device__ __forceinline__ short f2bf(float f) {
    union { float f; unsigned u; } v; v.f = f;
    unsigned u = v.u + 0x7fffu + ((v.u >> 16) & 1u);   // RNE
    return (short)(u >> 16);
}
__device__ __forceinline__ uint32 pack2bf(float lo, float hi) {
    return (uint32)(unsigned short)f2bf(lo) | ((uint32)(unsigned short)f2bf(hi) << 16);
}
// truncation pack: 3 ops; downward bias cancels in softmax ratio P/l
// (l is summed from these SAME truncated values via the ones-MFMA)
__device__ __forceinline__ uint32 pack2bf_trunc(float lo, float hi) {
    union { float f; uint32 u; } a, b; a.f = lo; b.f = hi;
    return (a.u >> 16) | (b.u & 0xffff0000u);
}

// ---------------------------------------------------------------------------
// Kernel 1: conv1x1 projections + 2x2 maxpool. z=0: theta(+log2e scale)+phi,
// z=1: g. Weights via wave-uniform global indices -> s_load + SGPR FMAs.
// V stored PRE-PERMUTED: within each 32-key chunk, slot(quad,j) =
//   j<4 ? quad*4+j : 16+quad*4+(j-4)  == PV MFMA A-frag order, so attn
// loads one bf16x8 per (chunk, quad) with every cache line fully used.
// ---------------------------------------------------------------------------
__global__ __launch_bounds__(256) void proj_kernel(
    const float* __restrict__ x, const float* __restrict__ wt,
    const float* __restrict__ wp, const float* __restrict__ wg,
    short* __restrict__ Qb, short* __restrict__ Kb, short* __restrict__ Vt)
{
    __shared__ float pg_lds[256][33];   // +1 pad
    int tid = threadIdx.x, z = blockIdx.z;
    int s = blockIdx.x, b = blockIdx.y;
    int r = tid >> 7, wc = tid & 127;
    int n = (2*s + r)*WW + wc;

    float xv[64];
    #pragma unroll
    for (int c = 0; c < 64; ++c) xv[c] = x[((b*CC + c) << 14) + n];

    if (z == 0) {
        float o8[8];
        #pragma unroll
        for (int o = 0; o < 8; ++o) {
            float a = 0.f;
            #pragma unroll
            for (int c = 0; c < 64; ++c) a += wt[o*64 + c]*xv[c];
            o8[o] = a*LOG2E;            // fold softmax exp->exp2
        }
        uint4 val;
        val.x = pack2bf(o8[0], o8[1]); val.y = pack2bf(o8[2], o8[3]);
        val.z = pack2bf(o8[4], o8[5]); val.w = pack2bf(o8[6], o8[7]);
        ((uint4*)Qb)[b*NN + n] = val;
        #pragma unroll
        for (int o = 0; o < 8; ++o) {
            float a = 0.f;
            #pragma unroll
            for (int c = 0; c < 64; ++c) a += wp[o*64 + c]*xv[c];
            pg_lds[tid][o] = a;
        }
        __syncthreads();
        if (tid < 64) {
            int w2 = tid, t00 = 2*w2, t01 = t00+1, t10 = 128+2*w2, t11 = t10+1;
            int m = s*64 + w2;
            float kf[8];
            #pragma unroll
            for (int o = 0; o < 8; ++o)
                kf[o] = fmaxf(fmaxf(pg_lds[t00][o], pg_lds[t01][o]),
                              fmaxf(pg_lds[t10][o], pg_lds[t11][o]));
            uint4 val2;
            val2.x = pack2bf(kf[0], kf[1]); val2.y = pack2bf(kf[2], kf[3]);
            val2.z = pack2bf(kf[4], kf[5]); val2.w = pack2bf(kf[6], kf[7]);
            ((uint4*)Kb)[b*MM + m] = val2;
        }
    } else {
        #pragma unroll
        for (int o = 0; o < 32; ++o) {
            float a = 0.f;
            #pragma unroll
            for (int c = 0; c < 64; ++c) a += wg[o*64 + c]*xv[c];
            pg_lds[tid][o] = a;
        }
        __syncthreads();
        int g = tid >> 6, w2 = tid & 63;
        int t00 = 2*w2, t01 = t00+1, t10 = 128+2*w2, t11 = t10+1;
        int m = s*64 + w2;
        // permuted position within the 32-key chunk
        int chunk = m >> 5, w = m & 31;
        int slot = ((w >> 2) & 3)*8 + (w & 3) + ((w >> 4) << 2);
        int pos = chunk*32 + slot;
        #pragma unroll
        for (int j = 0; j < 8; ++j) {
            int o = g*8 + j;
            float a = fmaxf(fmaxf(pg_lds[t00][o], pg_lds[t01][o]),
                            fmaxf(pg_lds[t10][o], pg_lds[t11][o]));
            Vt[(b*CV + o)*MM + pos] = f2bf(a);
        }
    }
}

// ---------------------------------------------------------------------------
// Kernel 2: fused attention + normalize + w_o + residual.
// __launch_bounds__(256,2): 256-VGPR budget at the 2 waves/SIMD the grid
// gives (R3's 56-VGPR squeeze serialized all prefetch loads — the 138us).
// l computed by a 3rd PV MFMA with all-ones A (every D row == l, no shuffle).
// Grid = B*N/64 = 512 blocks x 256 threads.
// ---------------------------------------------------------------------------
__global__ __launch_bounds__(256, 2) void attn_kernel(
    const short* __restrict__ Qb, const short* __restrict__ Kb,
    const short* __restrict__ Vt, const float* __restrict__ x,
    const float* __restrict__ wo, const float* __restrict__ gamma,
    float* __restrict__ out)
{
    int tid = threadIdx.x, wave = tid >> 6, lane = tid & 63;
    int quad = lane >> 4, c15 = lane & 15;
    int gq = blockIdx.x*4 + wave;
    int b = gq >> 10;
    int qbase = (gq & 1023) << 4;

    const f32x4 zero4 = {0.f, 0.f, 0.f, 0.f};
    bf16x8 zero8 = (bf16x8)0;
    U8 ones; ones.u[0] = 0x3F803F80u; ones.u[1] = 0x3F803F80u;
    ones.u[2] = 0x3F803F80u; ones.u[3] = 0x3F803F80u;

    // Q as score-MFMA B-operand: B[k=ch][n=q]; quads 1-3 MUST be zero.
    bf16x8 bq = (quad == 0) ? ((const bf16x8*)Qb)[b*NN + qbase + c15] : zero8;

    const short* Kbb = Kb + b*MM*8;
    const short* V0b = Vt + (b*CV + c15)*MM;        // ch = c15
    const short* V1b = Vt + (b*CV + 16 + c15)*MM;   // ch = 16+c15

    f32x4 D0 = zero4, D1 = zero4, Dl = zero4;

    // stage 0: 64 keys = 2 chunks of 32
    bf16x8 kc[4], av0[2], av1[2];
    #pragma unroll
    for (int h = 0; h < 2; ++h) {
        int k = h*32;
        kc[2*h]   = *(const bf16x8*)(Kbb + (k + c15)*8);
        kc[2*h+1] = *(const bf16x8*)(Kbb + (k + 16 + c15)*8);
        av0[h] = *(const bf16x8*)(V0b + k + quad*8);   // pre-permuted
        av1[h] = *(const bf16x8*)(V1b + k + quad*8);
    }

    #pragma unroll 2
    for (int sc = 0; sc < 64; ++sc) {
        int kn = (sc + 1)*64;
        kn = (kn > MM - 64) ? (MM - 64) : kn;   // scalar clamp, no branch
        bf16x8 nk[4], na0[2], na1[2];
        #pragma unroll
        for (int h = 0; h < 2; ++h) {
            int k = kn + h*32;
            nk[2*h]   = *(const bf16x8*)(Kbb + (k + c15)*8);
            nk[2*h+1] = *(const bf16x8*)(Kbb + (k + 16 + c15)*8);
            na0[h] = *(const bf16x8*)(V0b + k + quad*8);
            na1[h] = *(const bf16x8*)(V1b + k + quad*8);
        }
        #pragma unroll
        for (int h = 0; h < 2; ++h) {
            // S'[key][q]: C row = key-within = quad*4+r, col = q = c15
            f32x4 s0 = __builtin_amdgcn_mfma_f32_16x16x32_bf16(kc[2*h],   bq, zero4, 0, 0, 0);
            f32x4 s1 = __builtin_amdgcn_mfma_f32_16x16x32_bf16(kc[2*h+1], bq, zero4, 0, 0, 0);
            float p00 = __builtin_amdgcn_exp2f(s0[0]), p01 = __builtin_amdgcn_exp2f(s0[1]);
            float p02 = __builtin_amdgcn_exp2f(s0[2]), p03 = __builtin_amdgcn_exp2f(s0[3]);
            float p10 = __builtin_amdgcn_exp2f(s1[0]), p11 = __builtin_amdgcn_exp2f(s1[1]);
            float p12 = __builtin_amdgcn_exp2f(s1[2]), p13 = __builtin_amdgcn_exp2f(s1[3]);
            // P C-frags -> PV B-operand in permuted-slot order
            U8 bp;
            bp.u[0] = pack2bf_trunc(p00, p01); bp.u[1] = pack2bf_trunc(p02, p03);
            bp.u[2] = pack2bf_trunc(p10, p11); bp.u[3] = pack2bf_trunc(p12, p13);
            D0 = __builtin_amdgcn_mfma_f32_16x16x32_bf16(av0[h], bp.v, D0, 0, 0, 0);
            D1 = __builtin_amdgcn_mfma_f32_16x16x32_bf16(av1[h], bp.v, D1, 0, 0, 0);
            Dl = __builtin_amdgcn_mfma_f32_16x16x32_bf16(ones.v, bp.v, Dl, 0, 0, 0);
        }
        #pragma unroll
        for (int i = 0; i < 2; ++i) {
            kc[2*i] = nk[2*i]; kc[2*i+1] = nk[2*i+1];
            av0[i] = na0[i]; av1[i] = na1[i];
        }
    }

    // every row of Dl == l[q=c15]; D0/D1 cols are also q=c15 -> no shuffle
    float rl = 1.0f / Dl[0];

    U8 By;
    By.u[0] = pack2bf(D0[0]*rl, D0[1]*rl); By.u[1] = pack2bf(D0[2]*rl, D0[3]*rl);
    By.u[2] = pack2bf(D1[0]*rl, D1[1]*rl); By.u[3] = pack2bf(D1[2]*rl, D1[3]*rl);

    float gam = gamma[0];
    #pragma unroll
    for (int t = 0; t < 4; ++t) {
        int co = t*16 + c15;
        float4 wlo = *(const float4*)(wo + co*32 + quad*4);
        float4 whi = *(const float4*)(wo + co*32 + 16 + quad*4);
        U8 aw;
        aw.u[0] = pack2bf(wlo.x, wlo.y); aw.u[1] = pack2bf(wlo.z, wlo.w);
        aw.u[2] = pack2bf(whi.x, whi.y); aw.u[3] = pack2bf(whi.z, whi.w);
        f32x4 o2 = __builtin_amdgcn_mfma_f32_16x16x32_bf16(aw.v, By.v, zero4, 0, 0, 0);
        #pragma unroll
        for (int r2 = 0; r2 < 4; ++r2) {
            int co_r = t*16 + quad*4 + r2;
            int idx = ((b*CC + co_r) << 14) + qbase + c15;
            out[idx] = x[idx] + gam*o2[r2];
        }
    }
}

// ---------------------------------------------------------------------------
// Workspace: Qb 512K @ 0, Kb 128K @ 524288, Vt 512K @ 655360.
// ---------------------------------------------------------------------------
extern "C" void kernel_launch(void* const* d_in, const int* in_sizes, int n_in,
                              void* d_out, int out_size, void* d_ws, size_t ws_size,
                              hipStream_t stream) {
    const float* x     = (const float*)d_in[0];
    const float* wt    = (const float*)d_in[1];
    const float* wp    = (const float*)d_in[2];
    const float* wg    = (const float*)d_in[3];
    const float* wo    = (const float*)d_in[4];
    const float* gamma = (const float*)d_in[5];
    float* out = (float*)d_out;

    char* ws = (char*)d_ws;
    short* Qb = (short*)(ws);
    short* Kb = (short*)(ws + 524288);
    short* Vt = (short*)(ws + 655360);

    dim3 g1(HH/2, BB, 2);
    proj_kernel<<<g1, 256, 0, stream>>>(x, wt, wp, wg, Qb, Kb, Vt);
    attn_kernel<<<BB*NN/64, 256, 0, stream>>>(Qb, Kb, Vt, x, wo, gamma, out);
}

// Round 5
// 124.495 us; speedup vs baseline: 1.7936x; 1.4727x over previous
//
#include <hip/hip_runtime.h>

#define BB 2
#define CC 64
#define HH 128
#define WW 128
#define NN (HH*WW)          // 16384 queries per batch
#define MM ((HH/2)*(WW/2))  // 4096 keys per batch
#define CV 32
#define LOG2E 1.44269504088896f

typedef __attribute__((ext_vector_type(8))) short bf16x8;
typedef __attribute__((ext_vector_type(4))) float f32x4;
typedef unsigned int uint32;

union U8 { bf16x8 v; uint32 u[4]; };

__device__ __forceinline__ short f2bf(float f) {
    union { float f; unsigned u; } v; v.f = f;
    unsigned u = v.u + 0x7fffu + ((v.u >> 16) & 1u);   // RNE
    return (short)(u >> 16);
}
__device__ __forceinline__ uint32 pack2bf(float lo, float hi) {
    return (uint32)(unsigned short)f2bf(lo) | ((uint32)(unsigned short)f2bf(hi) << 16);
}
// 1-instr truncation pack via v_perm_b32; downward bias cancels in P/l ratio
__device__ __forceinline__ uint32 packperm(float lo, float hi) {
    union { float f; uint32 u; } a, b; a.f = lo; b.f = hi;
    return __builtin_amdgcn_perm(b.u, a.u, 0x07060302u);
}

// ---------------------------------------------------------------------------
// Kernel 1: conv1x1 projections + 2x2 maxpool. z=0: theta(*log2e)+phi, z=1: g.
// __launch_bounds__(256,2): WITHOUT it the 64-VGPR cap (8-wave target)
// spills xv[64] to scratch -> the constant ~85us across R1-R4.
// V global layout: per 64-key group, MFMA-A permuted slot + XOR swizzle
// (col8 ^= ch&7) so attn's LDS reads are conflict-free.
// ---------------------------------------------------------------------------
__global__ __launch_bounds__(256, 2) void proj_kernel(
    const float* __restrict__ x, const float* __restrict__ wt,
    const float* __restrict__ wp, const float* __restrict__ wg,
    short* __restrict__ Qb, short* __restrict__ Kb, short* __restrict__ Vt)
{
    __shared__ float pg_lds[256][33];   // +1 pad
    int tid = threadIdx.x, z = blockIdx.z;
    int s = blockIdx.x, b = blockIdx.y;
    int r = tid >> 7, wc = tid & 127;
    int n = (2*s + r)*WW + wc;

    float xv[64];
    #pragma unroll
    for (int c = 0; c < 64; ++c) xv[c] = x[((b*CC + c) << 14) + n];

    if (z == 0) {
        float o8[8];
        #pragma unroll
        for (int o = 0; o < 8; ++o) {
            float a = 0.f;
            #pragma unroll
            for (int c = 0; c < 64; ++c) a += wt[o*64 + c]*xv[c];
            o8[o] = a*LOG2E;            // fold softmax exp->exp2
        }
        uint4 val;
        val.x = pack2bf(o8[0], o8[1]); val.y = pack2bf(o8[2], o8[3]);
        val.z = pack2bf(o8[4], o8[5]); val.w = pack2bf(o8[6], o8[7]);
        ((uint4*)Qb)[b*NN + n] = val;
        #pragma unroll
        for (int o = 0; o < 8; ++o) {
            float a = 0.f;
            #pragma unroll
            for (int c = 0; c < 64; ++c) a += wp[o*64 + c]*xv[c];
            pg_lds[tid][o] = a;
        }
        __syncthreads();
        if (tid < 64) {
            int w2 = tid, t00 = 2*w2, t01 = t00+1, t10 = 128+2*w2, t11 = t10+1;
            int m = s*64 + w2;
            float kf[8];
            #pragma unroll
            for (int o = 0; o < 8; ++o)
                kf[o] = fmaxf(fmaxf(pg_lds[t00][o], pg_lds[t01][o]),
                              fmaxf(pg_lds[t10][o], pg_lds[t11][o]));
            uint4 val2;
            val2.x = pack2bf(kf[0], kf[1]); val2.y = pack2bf(kf[2], kf[3]);
            val2.z = pack2bf(kf[4], kf[5]); val2.w = pack2bf(kf[6], kf[7]);
            ((uint4*)Kb)[b*MM + m] = val2;
        }
    } else {
        #pragma unroll
        for (int o = 0; o < 32; ++o) {
            float a = 0.f;
            #pragma unroll
            for (int c = 0; c < 64; ++c) a += wg[o*64 + c]*xv[c];
            pg_lds[tid][o] = a;
        }
        __syncthreads();
        int g = tid >> 6, w2 = tid & 63;
        int t00 = 2*w2, t01 = t00+1, t10 = 128+2*w2, t11 = t10+1;
        int m = s*64 + w2;
        // MFMA-A permuted position within the 64-key group + XOR swizzle
        int grp = m >> 6, w64 = m & 63;
        int h = w64 >> 5, w = w64 & 31;
        int slot = ((w >> 2) & 3)*8 + (w & 3) + ((w >> 4) << 2);
        int pos64 = h*32 + slot;
        #pragma unroll
        for (int j = 0; j < 8; ++j) {
            int o = g*8 + j;
            float a = fmaxf(fmaxf(pg_lds[t00][o], pg_lds[t01][o]),
                            fmaxf(pg_lds[t10][o], pg_lds[t11][o]));
            int col = (pos64 >> 3) ^ (o & 7);
            Vt[(b*CV + o)*MM + grp*64 + col*8 + (pos64 & 7)] = f2bf(a);
        }
    }
}

// ---------------------------------------------------------------------------
// Kernel 2: fused attention + normalize + w_o + residual.
// K/V staged in LDS (double-buffered, shared by the block's 4 waves — they
// sweep identical keys). Each wave stages 16B/lane/stage: one live uint4,
// nothing for the compiler to sink (R4's 94us was sunk register prefetch).
// Grid = B*N/64 = 512 blocks x 256 threads, 2 blocks/CU.
// ---------------------------------------------------------------------------
__global__ __launch_bounds__(256, 2) void attn_kernel(
    const short* __restrict__ Qb, const short* __restrict__ Kb,
    const short* __restrict__ Vt, const float* __restrict__ x,
    const float* __restrict__ wo, const float* __restrict__ gamma,
    float* __restrict__ out)
{
    __shared__ short ldsK[2][512];      // 2 x 64 keys x 8ch
    __shared__ short ldsV[2][2048];     // 2 x 32ch x 64keys (xor-swizzled)
    int tid = threadIdx.x, wave = tid >> 6, lane = tid & 63;
    int quad = lane >> 4, c15 = lane & 15;
    int gq = blockIdx.x*4 + wave;
    int b = gq >> 10;
    int qbase = (gq & 1023) << 4;

    const f32x4 zero4 = {0.f, 0.f, 0.f, 0.f};
    bf16x8 zero8 = (bf16x8)0;
    U8 ones; ones.u[0] = ones.u[1] = ones.u[2] = ones.u[3] = 0x3F803F80u;

    // Q as score-MFMA B-operand: B[k=ch][n=q]; quads 1-3 MUST be zero.
    bf16x8 bq = (quad == 0) ? ((const bf16x8*)Qb)[b*NN + qbase + c15] : zero8;

    const short* Kbb = Kb + b*MM*8;
    const short* Vtb = Vt + b*CV*MM;

    // staging source/dest for THIS lane (advance by k0 each stage)
    const short* Vg = Vtb + (wave*8 + (lane >> 3))*MM + (lane & 7)*8;
    const short* Kg = Kbb + lane*8;
    short* myV0 = &ldsV[0][wave*512 + lane*8];
    short* myV1 = &ldsV[1][wave*512 + lane*8];
    short* myK0 = &ldsK[0][lane*8];
    short* myK1 = &ldsK[1][lane*8];

    // stage 0
    {
        uint4 v = *(const uint4*)Vg;
        *(uint4*)myV0 = v;
        if (wave == 0) { uint4 k = *(const uint4*)Kg; *(uint4*)myK0 = k; }
    }
    __syncthreads();

    f32x4 D0 = zero4, D1 = zero4, Dl = zero4;
    int sw = c15 & 7;

    for (int sc = 0; sc < 64; ++sc) {
        int k0n = (sc + 1)*64;
        k0n = (k0n > MM - 64) ? (MM - 64) : k0n;
        uint4 nv = *(const uint4*)(Vg + k0n);           // keys offset in shorts
        uint4 nk;
        if (wave == 0) nk = *(const uint4*)(Kg + k0n*8);

        const short* bk = (sc & 1) ? ldsK[1] : ldsK[0];
        const short* bv = (sc & 1) ? ldsV[1] : ldsV[0];
        #pragma unroll
        for (int h = 0; h < 2; ++h) {
            bf16x8 kf0 = *(const bf16x8*)(bk + (h*32 + c15)*8);
            bf16x8 kf1 = *(const bf16x8*)(bk + (h*32 + 16 + c15)*8);
            int col8 = ((h*4 + quad) ^ sw)*8;
            bf16x8 a0 = *(const bf16x8*)(bv + c15*64 + col8);
            bf16x8 a1 = *(const bf16x8*)(bv + (16 + c15)*64 + col8);
            // S'[key][q]: C row = key-within = quad*4+r, col = q = c15
            f32x4 s0 = __builtin_amdgcn_mfma_f32_16x16x32_bf16(kf0, bq, zero4, 0, 0, 0);
            f32x4 s1 = __builtin_amdgcn_mfma_f32_16x16x32_bf16(kf1, bq, zero4, 0, 0, 0);
            float p00 = __builtin_amdgcn_exp2f(s0[0]), p01 = __builtin_amdgcn_exp2f(s0[1]);
            float p02 = __builtin_amdgcn_exp2f(s0[2]), p03 = __builtin_amdgcn_exp2f(s0[3]);
            float p10 = __builtin_amdgcn_exp2f(s1[0]), p11 = __builtin_amdgcn_exp2f(s1[1]);
            float p12 = __builtin_amdgcn_exp2f(s1[2]), p13 = __builtin_amdgcn_exp2f(s1[3]);
            U8 bp;
            bp.u[0] = packperm(p00, p01); bp.u[1] = packperm(p02, p03);
            bp.u[2] = packperm(p10, p11); bp.u[3] = packperm(p12, p13);
            D0 = __builtin_amdgcn_mfma_f32_16x16x32_bf16(a0, bp.v, D0, 0, 0, 0);
            D1 = __builtin_amdgcn_mfma_f32_16x16x32_bf16(a1, bp.v, D1, 0, 0, 0);
            Dl = __builtin_amdgcn_mfma_f32_16x16x32_bf16(ones.v, bp.v, Dl, 0, 0, 0);
        }
        if (sc & 1) { *(uint4*)myV0 = nv; if (wave == 0) *(uint4*)myK0 = nk; }
        else        { *(uint4*)myV1 = nv; if (wave == 0) *(uint4*)myK1 = nk; }
        __syncthreads();
    }

    // every row of Dl == l[q=c15]; D0/D1 cols are also q=c15 -> no shuffle
    float rl = 1.0f / Dl[0];

    U8 By;
    By.u[0] = pack2bf(D0[0]*rl, D0[1]*rl); By.u[1] = pack2bf(D0[2]*rl, D0[3]*rl);
    By.u[2] = pack2bf(D1[0]*rl, D1[1]*rl); By.u[3] = pack2bf(D1[2]*rl, D1[3]*rl);

    float gam = gamma[0];
    #pragma unroll
    for (int t = 0; t < 4; ++t) {
        int co = t*16 + c15;
        float4 wlo = *(const float4*)(wo + co*32 + quad*4);
        float4 whi = *(const float4*)(wo + co*32 + 16 + quad*4);
        U8 aw;
        aw.u[0] = pack2bf(wlo.x, wlo.y); aw.u[1] = pack2bf(wlo.z, wlo.w);
        aw.u[2] = pack2bf(whi.x, whi.y); aw.u[3] = pack2bf(whi.z, whi.w);
        f32x4 o2 = __builtin_amdgcn_mfma_f32_16x16x32_bf16(aw.v, By.v, zero4, 0, 0, 0);
        #pragma unroll
        for (int r2 = 0; r2 < 4; ++r2) {
            int co_r = t*16 + quad*4 + r2;
            int idx = ((b*CC + co_r) << 14) + qbase + c15;
            out[idx] = x[idx] + gam*o2[r2];
        }
    }
}

// ---------------------------------------------------------------------------
// Workspace: Qb 512K @ 0, Kb 128K @ 524288, Vt 512K @ 655360.
// ---------------------------------------------------------------------------
extern "C" void kernel_launch(void* const* d_in, const int* in_sizes, int n_in,
                              void* d_out, int out_size, void* d_ws, size_t ws_size,
                              hipStream_t stream) {
    const float* x     = (const float*)d_in[0];
    const float* wt    = (const float*)d_in[1];
    const float* wp    = (const float*)d_in[2];
    const float* wg    = (const float*)d_in[3];
    const float* wo    = (const float*)d_in[4];
    const float* gamma = (const float*)d_in[5];
    float* out = (float*)d_out;

    char* ws = (char*)d_ws;
    short* Qb = (short*)(ws);
    short* Kb = (short*)(ws + 524288);
    short* Vt = (short*)(ws + 655360);

    dim3 g1(HH/2, BB, 2);
    proj_kernel<<<g1, 256, 0, stream>>>(x, wt, wp, wg, Qb, Kb, Vt);
    attn_kernel<<<BB*NN/64, 256, 0, stream>>>(Qb, Kb, Vt, x, wo, gamma, out);
}

// Round 6
// 105.316 us; speedup vs baseline: 2.1202x; 1.1821x over previous
//
#include <hip/hip_runtime.h>

#define BB 2
#define CC 64
#define HH 128
#define WW 128
#define NN (HH*WW)          // 16384 queries per batch
#define MM ((HH/2)*(WW/2))  // 4096 keys per batch
#define CV 32
#define LOG2E 1.44269504088896f

typedef __attribute__((ext_vector_type(8))) short bf16x8;
typedef __attribute__((ext_vector_type(4))) float f32x4;
typedef unsigned int uint32;

union U8 { bf16x8 v; uint32 u[4]; };

__device__ __forceinline__ short f2bf(float f) {
    union { float f; unsigned u; } v; v.f = f;
    unsigned u = v.u + 0x7fffu + ((v.u >> 16) & 1u);   // RNE
    return (short)(u >> 16);
}
__device__ __forceinline__ uint32 pack2bf(float lo, float hi) {
    return (uint32)(unsigned short)f2bf(lo) | ((uint32)(unsigned short)f2bf(hi) << 16);
}
// 1-instr truncation pack via v_perm_b32; downward bias cancels in P/l ratio
__device__ __forceinline__ uint32 packperm(float lo, float hi) {
    union { float f; uint32 u; } a, b; a.f = lo; b.f = hi;
    return __builtin_amdgcn_perm(b.u, a.u, 0x07060302u);
}

// ---------------------------------------------------------------------------
// Kernel 1 v3: conv1x1 + 2x2 maxpool, 4-way input-channel split.
// Block = 64 pixels (2 rows x 32 cols) x 4 channel-parts = 256 threads.
// Grid (256, B, 2) = 1024 blocks -> 4 waves/SIMD (R1-R5 proj was stuck at
// ~40us at 1 wave/SIMD regardless of weight path — structural fix).
// part = wave id -> weight indices wave-uniform -> s_load + SGPR FMAs.
// ---------------------------------------------------------------------------
__global__ __launch_bounds__(256, 4) void proj_kernel(
    const float* __restrict__ x, const float* __restrict__ wt,
    const float* __restrict__ wp, const float* __restrict__ wg,
    short* __restrict__ Qb, short* __restrict__ Kb, short* __restrict__ Vt)
{
    __shared__ float plds[8192];        // [o*4+part][px] partials (<=32KB)
    __shared__ float phi_lds[512];      // [phi_ch][px] for z=0 pooling
    int tid = threadIdx.x;
    int px = tid & 63, part = tid >> 6;
    int sb = blockIdx.x >> 2, cq = blockIdx.x & 3;
    int b = blockIdx.y, z = blockIdx.z;
    int row = px >> 5, col = cq*32 + (px & 31);
    int n = (2*sb + row)*WW + col;

    float xv[16];
    #pragma unroll
    for (int i = 0; i < 16; ++i)
        xv[i] = x[((b*CC + part*16 + i) << 14) + n];

    if (z == 0) {
        float po[16];
        #pragma unroll
        for (int o = 0; o < 8; ++o) {
            float a = 0.f;
            #pragma unroll
            for (int i = 0; i < 16; ++i) a += wt[o*64 + part*16 + i]*xv[i];
            po[o] = a;
        }
        #pragma unroll
        for (int o = 0; o < 8; ++o) {
            float a = 0.f;
            #pragma unroll
            for (int i = 0; i < 16; ++i) a += wp[o*64 + part*16 + i]*xv[i];
            po[8+o] = a;
        }
        #pragma unroll
        for (int o = 0; o < 16; ++o) plds[(o*4 + part)*64 + px] = po[o];
        __syncthreads();
        // combine 4 partials; og 0,1 -> theta to Qb; og 2,3 -> phi to LDS
        int og = tid >> 6;
        float sm[4];
        #pragma unroll
        for (int j = 0; j < 4; ++j) {
            int o = og*4 + j;
            sm[j] = (plds[(o*4+0)*64+px] + plds[(o*4+1)*64+px])
                  + (plds[(o*4+2)*64+px] + plds[(o*4+3)*64+px]);
        }
        if (og < 2) {
            uint2 val;
            val.x = pack2bf(sm[0]*LOG2E, sm[1]*LOG2E);
            val.y = pack2bf(sm[2]*LOG2E, sm[3]*LOG2E);
            ((uint2*)Qb)[(b*NN + n)*2 + og] = val;
        } else {
            #pragma unroll
            for (int j = 0; j < 4; ++j)
                phi_lds[((og-2)*4 + j)*64 + px] = sm[j];
        }
        __syncthreads();
        if (tid < 128) {   // pool phi: 16 m x 8 ch
            int mm = tid & 15, ch = tid >> 4;
            int p00 = 2*mm, p01 = p00+1, p10 = 32+2*mm, p11 = p10+1;
            float mx = fmaxf(fmaxf(phi_lds[ch*64+p00], phi_lds[ch*64+p01]),
                             fmaxf(phi_lds[ch*64+p10], phi_lds[ch*64+p11]));
            int m = sb*64 + cq*16 + mm;
            Kb[(b*MM + m)*8 + ch] = f2bf(mx);
        }
    } else {
        float po[32];
        #pragma unroll
        for (int o = 0; o < 32; ++o) {
            float a = 0.f;
            #pragma unroll
            for (int i = 0; i < 16; ++i) a += wg[o*64 + part*16 + i]*xv[i];
            po[o] = a;
        }
        #pragma unroll
        for (int o = 0; o < 32; ++o) plds[(o*4 + part)*64 + px] = po[o];
        __syncthreads();
        int og = tid >> 6;
        float sm[8];
        #pragma unroll
        for (int j = 0; j < 8; ++j) {
            int o = og*8 + j;
            sm[j] = (plds[(o*4+0)*64+px] + plds[(o*4+1)*64+px])
                  + (plds[(o*4+2)*64+px] + plds[(o*4+3)*64+px]);
        }
        __syncthreads();                 // all reads done before g-overwrite
        #pragma unroll
        for (int j = 0; j < 8; ++j)
            plds[(og*8 + j)*64 + px] = sm[j];   // g_lds[ch][px]
        __syncthreads();
        // pool g: 16 m x 32 ch = 512, 2 per thread
        int mm = tid & 15, chb = tid >> 4;      // chb 0..15 -> ch 2chb,2chb+1
        int p00 = 2*mm, p01 = p00+1, p10 = 32+2*mm, p11 = p10+1;
        int w64 = cq*16 + mm;
        int hh = w64 >> 5, w = w64 & 31;
        int slot = ((w >> 2) & 3)*8 + (w & 3) + ((w >> 4) << 2);
        int pos64 = hh*32 + slot;
        #pragma unroll
        for (int j = 0; j < 2; ++j) {
            int ch = chb*2 + j;
            float mx = fmaxf(fmaxf(plds[ch*64+p00], plds[ch*64+p01]),
                             fmaxf(plds[ch*64+p10], plds[ch*64+p11]));
            int colv = (pos64 >> 3) ^ (ch & 7);
            Vt[(b*CV + ch)*MM + sb*64 + colv*8 + (pos64 & 7)] = f2bf(mx);
        }
    }
}

// ---------------------------------------------------------------------------
// Kernel 2 v3: fused attention, 512-thr blocks = 4 q-tiles x 2 key-halves.
// Block stages BOTH half-windows in LDS (double-buffered) -> same L2
// traffic as R5 but 4 waves/SIMD (was 2) and 32 barriers/wave (was 64).
// Halves combined via LDS at the end; even waves run the w_o epilogue.
// Grid = B*N/64 = 512 blocks x 512 threads, 2 blocks/CU.
// ---------------------------------------------------------------------------
__global__ __launch_bounds__(512, 4) void attn_kernel(
    const short* __restrict__ Qb, const short* __restrict__ Kb,
    const short* __restrict__ Vt, const float* __restrict__ x,
    const float* __restrict__ wo, const float* __restrict__ gamma,
    float* __restrict__ out)
{
    __shared__ short ldsK[2][2][512];       // [buf][win][64key x 8ch]
    __shared__ short ldsV[2][2][2048];      // [buf][win][32ch x 64key]
    __shared__ float comb[4*64*9];          // stride 9: conflict-free
    int tid = threadIdx.x;
    int wave = tid >> 6, lane = tid & 63;
    int quad = lane >> 4, c15 = lane & 15;
    int qt = wave >> 1, half = wave & 1;
    int gq = blockIdx.x*4 + qt;
    int b = gq >> 10, qbase = (gq & 1023) << 4;

    const f32x4 zero4 = {0.f, 0.f, 0.f, 0.f};
    bf16x8 zero8 = (bf16x8)0;
    U8 ones; ones.u[0] = ones.u[1] = ones.u[2] = ones.u[3] = 0x3F803F80u;

    bf16x8 bq = (quad == 0) ? ((const bf16x8*)Qb)[b*NN + qbase + c15] : zero8;

    const short* Kbb = Kb + b*MM*8;
    const short* Vtb = Vt + b*CV*MM;

    // staging role (independent of compute role)
    int swin = tid >> 8;                    // window this thread stages
    int st = tid & 255, stw = st >> 6, stl = st & 63;
    const short* Vg = Vtb + (stw*8 + (stl >> 3))*MM + swin*2048 + (stl & 7)*8;
    const short* Kg = Kbb + swin*2048*8 + stl*8;
    int vdst = (stw*8 + (stl >> 3))*64 + (stl & 7)*8;
    int kdst = stl*8;

    {   // stage 0
        uint4 v = *(const uint4*)Vg;
        *(uint4*)&ldsV[0][swin][vdst] = v;
        if (stw == 0) { uint4 k = *(const uint4*)Kg; *(uint4*)&ldsK[0][swin][kdst] = k; }
    }
    __syncthreads();

    f32x4 D0 = zero4, D1 = zero4, Dl = zero4;
    int sw = c15 & 7;

    #pragma unroll 2
    for (int sc = 0; sc < 32; ++sc) {
        int scn = (sc + 1 > 31) ? 31 : sc + 1;
        uint4 nv = *(const uint4*)(Vg + scn*64);
        uint4 nk;
        if (stw == 0) nk = *(const uint4*)(Kg + scn*512);

        const short* bk = ldsK[sc & 1][half];
        const short* bv = ldsV[sc & 1][half];
        #pragma unroll
        for (int h = 0; h < 2; ++h) {
            bf16x8 kf0 = *(const bf16x8*)(bk + (h*32 + c15)*8);
            bf16x8 kf1 = *(const bf16x8*)(bk + (h*32 + 16 + c15)*8);
            int col8 = ((h*4 + quad) ^ sw)*8;
            bf16x8 a0 = *(const bf16x8*)(bv + c15*64 + col8);
            bf16x8 a1 = *(const bf16x8*)(bv + (16 + c15)*64 + col8);
            f32x4 s0 = __builtin_amdgcn_mfma_f32_16x16x32_bf16(kf0, bq, zero4, 0, 0, 0);
            f32x4 s1 = __builtin_amdgcn_mfma_f32_16x16x32_bf16(kf1, bq, zero4, 0, 0, 0);
            float p00 = __builtin_amdgcn_exp2f(s0[0]), p01 = __builtin_amdgcn_exp2f(s0[1]);
            float p02 = __builtin_amdgcn_exp2f(s0[2]), p03 = __builtin_amdgcn_exp2f(s0[3]);
            float p10 = __builtin_amdgcn_exp2f(s1[0]), p11 = __builtin_amdgcn_exp2f(s1[1]);
            float p12 = __builtin_amdgcn_exp2f(s1[2]), p13 = __builtin_amdgcn_exp2f(s1[3]);
            U8 bp;
            bp.u[0] = packperm(p00, p01); bp.u[1] = packperm(p02, p03);
            bp.u[2] = packperm(p10, p11); bp.u[3] = packperm(p12, p13);
            D0 = __builtin_amdgcn_mfma_f32_16x16x32_bf16(a0, bp.v, D0, 0, 0, 0);
            D1 = __builtin_amdgcn_mfma_f32_16x16x32_bf16(a1, bp.v, D1, 0, 0, 0);
            Dl = __builtin_amdgcn_mfma_f32_16x16x32_bf16(ones.v, bp.v, Dl, 0, 0, 0);
        }
        if (sc & 1) { *(uint4*)&ldsV[0][swin][vdst] = nv; if (stw == 0) *(uint4*)&ldsK[0][swin][kdst] = nk; }
        else        { *(uint4*)&ldsV[1][swin][vdst] = nv; if (stw == 0) *(uint4*)&ldsK[1][swin][kdst] = nk; }
        __syncthreads();
    }

    // combine the two key-halves of each q-tile
    if (half == 1) {
        float* c = &comb[(qt*64 + lane)*9];
        c[0] = D0[0]; c[1] = D0[1]; c[2] = D0[2]; c[3] = D0[3];
        c[4] = D1[0]; c[5] = D1[1]; c[6] = D1[2]; c[7] = D1[3];
        c[8] = Dl[0];
    }
    __syncthreads();
    if (half == 1) return;      // no further barriers — legal early exit
    float lsum;
    {
        const float* c = &comb[(qt*64 + lane)*9];
        D0[0] += c[0]; D0[1] += c[1]; D0[2] += c[2]; D0[3] += c[3];
        D1[0] += c[4]; D1[1] += c[5]; D1[2] += c[6]; D1[3] += c[7];
        lsum = Dl[0] + c[8];
    }
    float rl = 1.0f / lsum;

    U8 By;
    By.u[0] = pack2bf(D0[0]*rl, D0[1]*rl); By.u[1] = pack2bf(D0[2]*rl, D0[3]*rl);
    By.u[2] = pack2bf(D1[0]*rl, D1[1]*rl); By.u[3] = pack2bf(D1[2]*rl, D1[3]*rl);

    float gam = gamma[0];
    #pragma unroll
    for (int t = 0; t < 4; ++t) {
        int co = t*16 + c15;
        float4 wlo = *(const float4*)(wo + co*32 + quad*4);
        float4 whi = *(const float4*)(wo + co*32 + 16 + quad*4);
        U8 aw;
        aw.u[0] = pack2bf(wlo.x, wlo.y); aw.u[1] = pack2bf(wlo.z, wlo.w);
        aw.u[2] = pack2bf(whi.x, whi.y); aw.u[3] = pack2bf(whi.z, whi.w);
        f32x4 o2 = __builtin_amdgcn_mfma_f32_16x16x32_bf16(aw.v, By.v, zero4, 0, 0, 0);
        #pragma unroll
        for (int r2 = 0; r2 < 4; ++r2) {
            int co_r = t*16 + quad*4 + r2;
            int idx = ((b*CC + co_r) << 14) + qbase + c15;
            out[idx] = x[idx] + gam*o2[r2];
        }
    }
}

// ---------------------------------------------------------------------------
// Workspace: Qb 512K @ 0, Kb 128K @ 524288, Vt 512K @ 655360.
// ---------------------------------------------------------------------------
extern "C" void kernel_launch(void* const* d_in, const int* in_sizes, int n_in,
                              void* d_out, int out_size, void* d_ws, size_t ws_size,
                              hipStream_t stream) {
    const float* x     = (const float*)d_in[0];
    const float* wt    = (const float*)d_in[1];
    const float* wp    = (const float*)d_in[2];
    const float* wg    = (const float*)d_in[3];
    const float* wo    = (const float*)d_in[4];
    const float* gamma = (const float*)d_in[5];
    float* out = (float*)d_out;

    char* ws = (char*)d_ws;
    short* Qb = (short*)(ws);
    short* Kb = (short*)(ws + 524288);
    short* Vt = (short*)(ws + 655360);

    dim3 g1(256, BB, 2);
    proj_kernel<<<g1, 256, 0, stream>>>(x, wt, wp, wg, Qb, Kb, Vt);
    attn_kernel<<<BB*NN/64, 512, 0, stream>>>(Qb, Kb, Vt, x, wo, gamma, out);
}

// Round 7
// 104.969 us; speedup vs baseline: 2.1273x; 1.0033x over previous
//
#include <hip/hip_runtime.h>

#define BB 2
#define CC 64
#define HH 128
#define WW 128
#define NN (HH*WW)          // 16384 queries per batch
#define MM ((HH/2)*(WW/2))  // 4096 keys per batch
#define CV 32
#define LOG2E 1.44269504088896f

typedef __attribute__((ext_vector_type(8))) short bf16x8;
typedef __attribute__((ext_vector_type(4))) float f32x4;
typedef unsigned int uint32;

union U8 { bf16x8 v; uint32 u[4]; };

__device__ __forceinline__ short f2bf(float f) {
    union { float f; unsigned u; } v; v.f = f;
    unsigned u = v.u + 0x7fffu + ((v.u >> 16) & 1u);   // RNE
    return (short)(u >> 16);
}
__device__ __forceinline__ uint32 pack2bf(float lo, float hi) {
    return (uint32)(unsigned short)f2bf(lo) | ((uint32)(unsigned short)f2bf(hi) << 16);
}
// 1-instr truncation pack via v_perm_b32; downward bias cancels in P/l ratio
__device__ __forceinline__ uint32 packperm(float lo, float hi) {
    union { float f; uint32 u; } a, b; a.f = lo; b.f = hi;
    return __builtin_amdgcn_perm(b.u, a.u, 0x07060302u);
}

// ---------------------------------------------------------------------------
// Kernel 1 (unchanged from R6): conv1x1 + 2x2 maxpool, 4-way channel split.
// ---------------------------------------------------------------------------
__global__ __launch_bounds__(256, 4) void proj_kernel(
    const float* __restrict__ x, const float* __restrict__ wt,
    const float* __restrict__ wp, const float* __restrict__ wg,
    short* __restrict__ Qb, short* __restrict__ Kb, short* __restrict__ Vt)
{
    __shared__ float plds[8192];
    __shared__ float phi_lds[512];
    int tid = threadIdx.x;
    int px = tid & 63, part = tid >> 6;
    int sb = blockIdx.x >> 2, cq = blockIdx.x & 3;
    int b = blockIdx.y, z = blockIdx.z;
    int row = px >> 5, col = cq*32 + (px & 31);
    int n = (2*sb + row)*WW + col;

    float xv[16];
    #pragma unroll
    for (int i = 0; i < 16; ++i)
        xv[i] = x[((b*CC + part*16 + i) << 14) + n];

    if (z == 0) {
        float po[16];
        #pragma unroll
        for (int o = 0; o < 8; ++o) {
            float a = 0.f;
            #pragma unroll
            for (int i = 0; i < 16; ++i) a += wt[o*64 + part*16 + i]*xv[i];
            po[o] = a;
        }
        #pragma unroll
        for (int o = 0; o < 8; ++o) {
            float a = 0.f;
            #pragma unroll
            for (int i = 0; i < 16; ++i) a += wp[o*64 + part*16 + i]*xv[i];
            po[8+o] = a;
        }
        #pragma unroll
        for (int o = 0; o < 16; ++o) plds[(o*4 + part)*64 + px] = po[o];
        __syncthreads();
        int og = tid >> 6;
        float sm[4];
        #pragma unroll
        for (int j = 0; j < 4; ++j) {
            int o = og*4 + j;
            sm[j] = (plds[(o*4+0)*64+px] + plds[(o*4+1)*64+px])
                  + (plds[(o*4+2)*64+px] + plds[(o*4+3)*64+px]);
        }
        if (og < 2) {
            uint2 val;
            val.x = pack2bf(sm[0]*LOG2E, sm[1]*LOG2E);
            val.y = pack2bf(sm[2]*LOG2E, sm[3]*LOG2E);
            ((uint2*)Qb)[(b*NN + n)*2 + og] = val;
        } else {
            #pragma unroll
            for (int j = 0; j < 4; ++j)
                phi_lds[((og-2)*4 + j)*64 + px] = sm[j];
        }
        __syncthreads();
        if (tid < 128) {
            int mm = tid & 15, ch = tid >> 4;
            int p00 = 2*mm, p01 = p00+1, p10 = 32+2*mm, p11 = p10+1;
            float mx = fmaxf(fmaxf(phi_lds[ch*64+p00], phi_lds[ch*64+p01]),
                             fmaxf(phi_lds[ch*64+p10], phi_lds[ch*64+p11]));
            int m = sb*64 + cq*16 + mm;
            Kb[(b*MM + m)*8 + ch] = f2bf(mx);
        }
    } else {
        float po[32];
        #pragma unroll
        for (int o = 0; o < 32; ++o) {
            float a = 0.f;
            #pragma unroll
            for (int i = 0; i < 16; ++i) a += wg[o*64 + part*16 + i]*xv[i];
            po[o] = a;
        }
        #pragma unroll
        for (int o = 0; o < 32; ++o) plds[(o*4 + part)*64 + px] = po[o];
        __syncthreads();
        int og = tid >> 6;
        float sm[8];
        #pragma unroll
        for (int j = 0; j < 8; ++j) {
            int o = og*8 + j;
            sm[j] = (plds[(o*4+0)*64+px] + plds[(o*4+1)*64+px])
                  + (plds[(o*4+2)*64+px] + plds[(o*4+3)*64+px]);
        }
        __syncthreads();
        #pragma unroll
        for (int j = 0; j < 8; ++j)
            plds[(og*8 + j)*64 + px] = sm[j];
        __syncthreads();
        int mm = tid & 15, chb = tid >> 4;
        int p00 = 2*mm, p01 = p00+1, p10 = 32+2*mm, p11 = p10+1;
        int w64 = cq*16 + mm;
        int hh = w64 >> 5, w = w64 & 31;
        int slot = ((w >> 2) & 3)*8 + (w & 3) + ((w >> 4) << 2);
        int pos64 = hh*32 + slot;
        #pragma unroll
        for (int j = 0; j < 2; ++j) {
            int ch = chb*2 + j;
            float mx = fmaxf(fmaxf(plds[ch*64+p00], plds[ch*64+p01]),
                             fmaxf(plds[ch*64+p10], plds[ch*64+p11]));
            int colv = (pos64 >> 3) ^ (ch & 7);
            Vt[(b*CV + ch)*MM + sb*64 + colv*8 + (pos64 & 7)] = f2bf(mx);
        }
    }
}

// ---------------------------------------------------------------------------
// Kernel 2 v4: 32 queries per wave (2 tiles share every LDS fragment read
// -> LDS issue per unit work halves vs R6), 4 quarter-windows of 1024 keys.
// Block = 512 thr = 2 qpairs x 4 quarters; 16 stages x 64 keys, 1 barrier
// each; quarter partials combined via stride-9 LDS; quarter-0 waves run the
// fused normalize+w_o+residual epilogue. Grid = 512 blocks, 4 waves/SIMD.
// ---------------------------------------------------------------------------
__global__ __launch_bounds__(512, 4) void attn_kernel(
    const short* __restrict__ Qb, const short* __restrict__ Kb,
    const short* __restrict__ Vt, const float* __restrict__ x,
    const float* __restrict__ wo, const float* __restrict__ gamma,
    float* __restrict__ out)
{
    __shared__ short ldsK[2][4][512];    // [buf][qtr][64key x 8ch]
    __shared__ short ldsV[2][4][2048];   // [buf][qtr][32ch x 64key swizzled]
    __shared__ float comb[2][2][576];    // [qpair][tile][lane*9]
    int tid = threadIdx.x;
    int wave = tid >> 6, lane = tid & 63;
    int quad = lane >> 4, c15 = lane & 15, sw = c15 & 7;
    int qtr = wave >> 1, qpair = wave & 1;
    int blk = blockIdx.x;
    int b = blk >> 8;
    int qblk = (blk & 255)*64;
    int q0 = qblk + qpair*32;            // tiles q0, q0+16

    const f32x4 zero4 = {0.f, 0.f, 0.f, 0.f};
    bf16x8 zero8 = (bf16x8)0;
    U8 ones; ones.u[0] = ones.u[1] = ones.u[2] = ones.u[3] = 0x3F803F80u;

    bf16x8 bq0 = (quad == 0) ? ((const bf16x8*)Qb)[b*NN + q0 + c15]      : zero8;
    bf16x8 bq1 = (quad == 0) ? ((const bf16x8*)Qb)[b*NN + q0 + 16 + c15] : zero8;

    // staging roles
    int sqtr = tid >> 7, sub = tid & 127;
    int sch = sub >> 2, spart = sub & 3;
    const short* Vg = Vt + ((size_t)b*CV + sch)*MM + sqtr*1024 + spart*16;
    int vofs = sch*64 + spart*16;
    int kqtr = tid >> 6, kofs = (tid & 63)*8;
    const short* Kg = Kb + (size_t)b*MM*8 + (kqtr*1024 + (tid & 63))*8;

    {   // stage 0
        uint4 v0 = *(const uint4*)(Vg);
        uint4 v1 = *(const uint4*)(Vg + 8);
        *(uint4*)&ldsV[0][sqtr][vofs]     = v0;
        *(uint4*)&ldsV[0][sqtr][vofs + 8] = v1;
        if (tid < 256) { uint4 k = *(const uint4*)Kg; *(uint4*)&ldsK[0][kqtr][kofs] = k; }
    }
    __syncthreads();

    f32x4 D0A = zero4, D1A = zero4, DlA = zero4;
    f32x4 D0B = zero4, D1B = zero4, DlB = zero4;

    for (int sc = 0; sc < 16; ++sc) {
        int scn = (sc + 1 > 15) ? 15 : sc + 1;
        uint4 nv0 = *(const uint4*)(Vg + scn*64);
        uint4 nv1 = *(const uint4*)(Vg + scn*64 + 8);
        uint4 nk;
        if (tid < 256) nk = *(const uint4*)(Kg + scn*512);

        const short* bk = ldsK[sc & 1][qtr];
        const short* bv = ldsV[sc & 1][qtr];
        #pragma unroll
        for (int h = 0; h < 2; ++h) {
            bf16x8 kf0 = *(const bf16x8*)(bk + (h*32 + c15)*8);
            bf16x8 kf1 = *(const bf16x8*)(bk + (h*32 + 16 + c15)*8);
            int col8 = ((h*4 + quad) ^ sw)*8;
            bf16x8 a0 = *(const bf16x8*)(bv + c15*64 + col8);
            bf16x8 a1 = *(const bf16x8*)(bv + (16 + c15)*64 + col8);
            f32x4 s0A = __builtin_amdgcn_mfma_f32_16x16x32_bf16(kf0, bq0, zero4, 0, 0, 0);
            f32x4 s1A = __builtin_amdgcn_mfma_f32_16x16x32_bf16(kf1, bq0, zero4, 0, 0, 0);
            f32x4 s0B = __builtin_amdgcn_mfma_f32_16x16x32_bf16(kf0, bq1, zero4, 0, 0, 0);
            f32x4 s1B = __builtin_amdgcn_mfma_f32_16x16x32_bf16(kf1, bq1, zero4, 0, 0, 0);
            U8 bpA, bpB;
            bpA.u[0] = packperm(__builtin_amdgcn_exp2f(s0A[0]), __builtin_amdgcn_exp2f(s0A[1]));
            bpA.u[1] = packperm(__builtin_amdgcn_exp2f(s0A[2]), __builtin_amdgcn_exp2f(s0A[3]));
            bpA.u[2] = packperm(__builtin_amdgcn_exp2f(s1A[0]), __builtin_amdgcn_exp2f(s1A[1]));
            bpA.u[3] = packperm(__builtin_amdgcn_exp2f(s1A[2]), __builtin_amdgcn_exp2f(s1A[3]));
            bpB.u[0] = packperm(__builtin_amdgcn_exp2f(s0B[0]), __builtin_amdgcn_exp2f(s0B[1]));
            bpB.u[1] = packperm(__builtin_amdgcn_exp2f(s0B[2]), __builtin_amdgcn_exp2f(s0B[3]));
            bpB.u[2] = packperm(__builtin_amdgcn_exp2f(s1B[0]), __builtin_amdgcn_exp2f(s1B[1]));
            bpB.u[3] = packperm(__builtin_amdgcn_exp2f(s1B[2]), __builtin_amdgcn_exp2f(s1B[3]));
            D0A = __builtin_amdgcn_mfma_f32_16x16x32_bf16(a0, bpA.v, D0A, 0, 0, 0);
            D1A = __builtin_amdgcn_mfma_f32_16x16x32_bf16(a1, bpA.v, D1A, 0, 0, 0);
            DlA = __builtin_amdgcn_mfma_f32_16x16x32_bf16(ones.v, bpA.v, DlA, 0, 0, 0);
            D0B = __builtin_amdgcn_mfma_f32_16x16x32_bf16(a0, bpB.v, D0B, 0, 0, 0);
            D1B = __builtin_amdgcn_mfma_f32_16x16x32_bf16(a1, bpB.v, D1B, 0, 0, 0);
            DlB = __builtin_amdgcn_mfma_f32_16x16x32_bf16(ones.v, bpB.v, DlB, 0, 0, 0);
        }
        int nb = (sc + 1) & 1;
        *(uint4*)&ldsV[nb][sqtr][vofs]     = nv0;
        *(uint4*)&ldsV[nb][sqtr][vofs + 8] = nv1;
        if (tid < 256) *(uint4*)&ldsK[nb][kqtr][kofs] = nk;
        __syncthreads();
    }

    // combine 4 quarter partials (stride-9: conflict-free)
    #pragma unroll
    for (int r = 1; r < 4; ++r) {
        if (qtr == r) {
            float* cA = &comb[qpair][0][lane*9];
            cA[0]=D0A[0]; cA[1]=D0A[1]; cA[2]=D0A[2]; cA[3]=D0A[3];
            cA[4]=D1A[0]; cA[5]=D1A[1]; cA[6]=D1A[2]; cA[7]=D1A[3];
            cA[8]=DlA[0];
            float* cB = &comb[qpair][1][lane*9];
            cB[0]=D0B[0]; cB[1]=D0B[1]; cB[2]=D0B[2]; cB[3]=D0B[3];
            cB[4]=D1B[0]; cB[5]=D1B[1]; cB[6]=D1B[2]; cB[7]=D1B[3];
            cB[8]=DlB[0];
        }
        __syncthreads();
        if (qtr == 0) {
            const float* cA = &comb[qpair][0][lane*9];
            D0A[0]+=cA[0]; D0A[1]+=cA[1]; D0A[2]+=cA[2]; D0A[3]+=cA[3];
            D1A[0]+=cA[4]; D1A[1]+=cA[5]; D1A[2]+=cA[6]; D1A[3]+=cA[7];
            DlA[0]+=cA[8];
            const float* cB = &comb[qpair][1][lane*9];
            D0B[0]+=cB[0]; D0B[1]+=cB[1]; D0B[2]+=cB[2]; D0B[3]+=cB[3];
            D1B[0]+=cB[4]; D1B[1]+=cB[5]; D1B[2]+=cB[6]; D1B[3]+=cB[7];
            DlB[0]+=cB[8];
        }
        __syncthreads();
    }
    if (qtr != 0) return;       // no barriers past this point

    float rlA = 1.0f / DlA[0];
    float rlB = 1.0f / DlB[0];
    U8 ByA, ByB;
    ByA.u[0] = pack2bf(D0A[0]*rlA, D0A[1]*rlA); ByA.u[1] = pack2bf(D0A[2]*rlA, D0A[3]*rlA);
    ByA.u[2] = pack2bf(D1A[0]*rlA, D1A[1]*rlA); ByA.u[3] = pack2bf(D1A[2]*rlA, D1A[3]*rlA);
    ByB.u[0] = pack2bf(D0B[0]*rlB, D0B[1]*rlB); ByB.u[1] = pack2bf(D0B[2]*rlB, D0B[3]*rlB);
    ByB.u[2] = pack2bf(D1B[0]*rlB, D1B[1]*rlB); ByB.u[3] = pack2bf(D1B[2]*rlB, D1B[3]*rlB);

    float gam = gamma[0];
    #pragma unroll
    for (int t = 0; t < 4; ++t) {
        int co = t*16 + c15;
        float4 wlo = *(const float4*)(wo + co*32 + quad*4);
        float4 whi = *(const float4*)(wo + co*32 + 16 + quad*4);
        U8 aw;
        aw.u[0] = pack2bf(wlo.x, wlo.y); aw.u[1] = pack2bf(wlo.z, wlo.w);
        aw.u[2] = pack2bf(whi.x, whi.y); aw.u[3] = pack2bf(whi.z, whi.w);
        f32x4 oA = __builtin_amdgcn_mfma_f32_16x16x32_bf16(aw.v, ByA.v, zero4, 0, 0, 0);
        f32x4 oB = __builtin_amdgcn_mfma_f32_16x16x32_bf16(aw.v, ByB.v, zero4, 0, 0, 0);
        #pragma unroll
        for (int r2 = 0; r2 < 4; ++r2) {
            int co_r = t*16 + quad*4 + r2;
            int base = ((b*CC + co_r) << 14) + q0 + c15;
            out[base]      = x[base]      + gam*oA[r2];
            out[base + 16] = x[base + 16] + gam*oB[r2];
        }
    }
}

// ---------------------------------------------------------------------------
// Workspace: Qb 512K @ 0, Kb 128K @ 524288, Vt 512K @ 655360.
// ---------------------------------------------------------------------------
extern "C" void kernel_launch(void* const* d_in, const int* in_sizes, int n_in,
                              void* d_out, int out_size, void* d_ws, size_t ws_size,
                              hipStream_t stream) {
    const float* x     = (const float*)d_in[0];
    const float* wt    = (const float*)d_in[1];
    const float* wp    = (const float*)d_in[2];
    const float* wg    = (const float*)d_in[3];
    const float* wo    = (const float*)d_in[4];
    const float* gamma = (const float*)d_in[5];
    float* out = (float*)d_out;

    char* ws = (char*)d_ws;
    short* Qb = (short*)(ws);
    short* Kb = (short*)(ws + 524288);
    short* Vt = (short*)(ws + 655360);

    dim3 g1(256, BB, 2);
    proj_kernel<<<g1, 256, 0, stream>>>(x, wt, wp, wg, Qb, Kb, Vt);
    attn_kernel<<<BB*NN/64, 512, 0, stream>>>(Qb, Kb, Vt, x, wo, gamma, out);
}